// Round 1
// 243.663 us; speedup vs baseline: 1.0216x; 1.0216x over previous
//
#include <hip/hip_runtime.h>

// Problem constants (match reference)
#define BB 2
#define CC 64
#define HH 512
#define WW 512
#define NN 4096
#define KK 5
#define HWp (HH * WW)

// ---------------------------------------------------------------------------
// Pass 1: gather OTHER-image features only into compact Fo [B][N][C].
// (Fr staging removed: each Fr row was consumed by exactly one loss wave, so
// its gather is fused into the loss kernel where the scattered-load latency
// hides under 32 waves/CU. Fo rows are reused ~6x -> compaction still pays.)
// wave = (b, point-group g, channel-chunk of 16). lane = point.
//  - 16 independent strided gathers per lane in flight (latency hiding)
//  - lane's 16 results -> four float4 stores to ONE 64 B line (coalesced)
//  - NONTEMPORAL reads: single-use random lines must not evict Fo from the
//    4 MiB/XCD L2 (loss pass re-reads Fo ~6x)
//  - 256 blocks x 128 threads: 2 waves/block spread over all 256 CUs
// NOTE (earlier post-mortem): no per-block agent-scope acq/rel — each pair
// costs a full L2 writeback/invalidate on gfx950; the implicit kernel-boundary
// flush is the cheap way to pass Fo between passes.
// ---------------------------------------------------------------------------
__global__ __launch_bounds__(128) void gather_kernel(
    const float* __restrict__ inputs_other,
    const int*   __restrict__ inds_other,
    float*       __restrict__ Fo)      // [B][N][C]
{
    const int lane = threadIdx.x & 63;
    int w = (blockIdx.x * 128 + threadIdx.x) >> 6;   // wave id, 0..511
    const int chunk = w & 3;  w >>= 2;   // 4 chunks of 16 channels
    const int g     = w & 63; w >>= 6;   // N/64 = 64 point groups
    const int b     = w;                 // B = 2

    const int i = g * 64 + lane;
    const int* ind = inds_other + b * 2 * NN;
    const int lin = HH * ind[NN + i] + ind[i];       // H*y + x

    const float* src = inputs_other
                       + (size_t)b * CC * HWp
                       + (size_t)chunk * 16 * HWp
                       + lin;
    float v[16];
#pragma unroll
    for (int cc = 0; cc < 16; ++cc)
        v[cc] = __builtin_nontemporal_load(src + (size_t)cc * HWp);

    float* dst = Fo + (size_t)(b * NN + i) * CC + chunk * 16;
#pragma unroll
    for (int q = 0; q < 4; ++q)
        ((float4*)dst)[q] = make_float4(v[4*q], v[4*q+1], v[4*q+2], v[4*q+3]);
}

// ---------------------------------------------------------------------------
// Pass 2: one wave per match point, lane = channel.
//  - fr gathered DIRECTLY from inputs_ref (lane = channel -> 64 scattered
//    4 B loads per wave, nontemporal). Same HBM amplification as the old
//    staging pass, but latency hides under this kernel's high occupancy and
//    we skip the 2 MB Fr write + 2 MB Fr read round-trip.
//  - fo + 5 mismatch vectors are contiguous 256 B reads from L2-resident Fo.
// Per-block partial written to ws (no global atomics, no agent-scope fences).
// ---------------------------------------------------------------------------
__global__ __launch_bounds__(256) void loss_kernel(
    const float* __restrict__ inputs_ref,
    const float* __restrict__ Fo,
    const float* __restrict__ weights,
    const int*   __restrict__ inds_ref,
    const int*   __restrict__ rand_inds,
    float*       __restrict__ partials)  // [gridDim.x]
{
    const int tid  = threadIdx.x;
    const int lane = tid & 63;
    const int wave = tid >> 6;                 // 4 waves / block
    const int gidx = blockIdx.x * 4 + wave;    // point index in [0, B*N)
    const int b = gidx >> 12;                  // NN = 4096 = 2^12
    const int i = gidx & (NN - 1);

    const int* ir = inds_ref + b * 2 * NN;     // x at [i], y at [NN+i]
    const int xr = ir[i];
    const int yr = ir[NN + i];
    const int lin = HH * yr + xr;

    // fused fr gather: lane = channel, stride HWp between lanes (64 lines/wave)
    const float fr = __builtin_nontemporal_load(
        inputs_ref + (size_t)(b * CC + lane) * HWp + lin);

    const float fo = Fo[(size_t)(b * NN + i) * CC + lane];
    const int* rj = rand_inds + (size_t)(b * NN + i) * KK;

    float s[1 + KK];
    float dist[KK];
    { const float d = fr - fo; s[0] = d * d; }
#pragma unroll
    for (int k = 0; k < KK; ++k) {
        const int j = rj[k];                               // wave-uniform
        const float fm = Fo[(size_t)(b * NN + j) * CC + lane];
        const float t = fr - fm;
        s[1 + k] = t * t;
        const float dx = (float)(xr - ir[j]);
        const float dy = (float)(yr - ir[NN + j]);
        dist[k] = sqrtf(dx * dx + dy * dy);
    }

    // 64-lane sum reductions for the 6 squared feature distances
#pragma unroll
    for (int r = 0; r < 1 + KK; ++r) {
        float v = s[r];
#pragma unroll
        for (int off = 32; off > 0; off >>= 1)
            v += __shfl_xor(v, off, 64);
        s[r] = v;
    }

    __shared__ float part[4];
    if (lane == 0) {
        const float max_distance = 724.07734f;   // sqrt(512^2+512^2)
        const float thr_nomatch  = 16.0f;        // 0.5^2 * C
        float acc = weights[b * NN + i] * fmaxf(s[0], 0.0f);
#pragma unroll
        for (int k = 0; k < KK; ++k) {
            // w_mm = -NON_MATCH_WEIGHT * d / max_dist / K, weight==K==5
            acc += (-dist[k] / max_distance) * fminf(s[1 + k], thr_nomatch);
        }
        part[wave] = acc * (1.0f / (float)((KK + 1) * NN));
    }
    __syncthreads();
    if (tid == 0)
        partials[blockIdx.x] = part[0] + part[1] + part[2] + part[3];
}

// ---------------------------------------------------------------------------
// Final: one block reduces the 2048 per-block partials and writes out[0]
// (overwrites the harness's 0xAA poison; no zero kernel needed).
// ---------------------------------------------------------------------------
__global__ __launch_bounds__(256) void reduce_kernel(
    const float* __restrict__ partials, int n, float* __restrict__ out)
{
    const int tid = threadIdx.x;
    float v = 0.0f;
    for (int idx = tid; idx < n; idx += 256)
        v += partials[idx];
#pragma unroll
    for (int off = 32; off > 0; off >>= 1)
        v += __shfl_xor(v, off, 64);
    __shared__ float part[4];
    if ((tid & 63) == 0) part[tid >> 6] = v;
    __syncthreads();
    if (tid == 0)
        out[0] = part[0] + part[1] + part[2] + part[3];
}

extern "C" void kernel_launch(void* const* d_in, const int* in_sizes, int n_in,
                              void* d_out, int out_size, void* d_ws, size_t ws_size,
                              hipStream_t stream) {
    const float* inputs_ref   = (const float*)d_in[0];
    const float* inputs_other = (const float*)d_in[1];
    const float* weights      = (const float*)d_in[2];
    const int*   inds_ref     = (const int*)d_in[3];
    const int*   inds_other   = (const int*)d_in[4];
    const int*   rand_inds    = (const int*)d_in[5];
    float* out = (float*)d_out;

    // workspace layout: Fo [B][N][C] (2 MB), partials 8 KB
    float* Fo = (float*)d_ws;
    float* partials = Fo + (size_t)BB * NN * CC;

    // pass 1: 2(b)*64(g)*4(chunk) = 512 waves -> 256 blocks x 128 threads
    gather_kernel<<<256, 128, 0, stream>>>(inputs_other, inds_other, Fo);

    // pass 2: B*N = 8192 waves -> 2048 blocks, per-block partials
    loss_kernel<<<2048, 256, 0, stream>>>(
        inputs_ref, Fo, weights, inds_ref, rand_inds, partials);

    // pass 3: single-block tree reduction -> out[0]
    reduce_kernel<<<1, 256, 0, stream>>>(partials, 2048, out);
}